// Round 3
// baseline (244.070 us; speedup 1.0000x reference)
//
#include <hip/hip_runtime.h>

typedef __attribute__((ext_vector_type(8))) short short8;
typedef __attribute__((ext_vector_type(4))) float f32x4;

constexpr int B_ = 4, T_ = 12, N_ = 2000, K_ = 10, F_ = 64, H_ = 8;
constexpr int AST = 72;   // A-tile LDS row stride (bf16 elems): 144B rows, 16B-aligned, 2-way-free writes
constexpr int CST = 68;   // C-tile stride (fp32): 272B rows, 16B-aligned, bank-balanced b128 reads

// fp32 -> bf16 (RNE) and back, bit ops
static __device__ __forceinline__ short f2bf(float f) {
    unsigned u = __float_as_uint(f);
    unsigned r = (u + 0x7FFFu + ((u >> 16) & 1u)) >> 16;
    return (short)(r & 0xFFFFu);
}
static __device__ __forceinline__ float bf2f(short s) {
    return __uint_as_float(((unsigned)(unsigned short)s) << 16);
}

__global__ __launch_bounds__(256, 4)
void gconv_mfma(const float* __restrict__ x,
                const float* __restrict__ dist,
                const float* __restrict__ W,
                const float* __restrict__ bias,
                const int*   __restrict__ idx,
                float* __restrict__ out)
{
    // A-tile (bf16 hi/lo) and C-tile (fp32) are live in disjoint phases -> alias them.
    __shared__ union {
        struct { short Ahi[96 * AST]; short Alo[96 * AST]; } ab;   // 27.6 KB
        float Cst[96 * CST];                                        // 26.1 KB
    } sm;
    __shared__ float bnd[4][H_][F_];   // 8 KB: raw agg row t=3w+2 for next wave's blend

    const int tid  = threadIdx.x;
    const int wave = tid >> 6;
    const int lane = tid & 63;
    const int n = blockIdx.x % N_;
    const int b = blockIdx.x / N_;
    const int t0 = wave * 3;           // wave owns t in [t0, t0+3)

    // ---- neighbor indices (block-uniform) + base weights r_k = exp(-d^2/288) ----
    float rk[K_];
    int   nb[K_];
    #pragma unroll
    for (int k = 0; k < K_; ++k) {
        nb[k] = idx[n * K_ + k] * F_;
        float d = dist[n * K_ + k];
        rk[k] = __expf(d * d * (-1.0f / 288.0f));
    }

    // ---- Phase 1: gather-FMA; wave covers 3 t's x all 8 heads, f = lane ----
    float acc[3][H_];
    #pragma unroll
    for (int i = 0; i < 3; ++i)
        #pragma unroll
        for (int h = 0; h < H_; ++h) acc[i][h] = 0.f;

    const float* xb = x + ((size_t)b * T_ + t0) * (size_t)(N_ * F_) + lane;
    #pragma unroll
    for (int k = 0; k < K_; ++k) {
        float x0 = xb[nb[k]];
        float x1 = xb[nb[k] + N_ * F_];
        float x2 = xb[nb[k] + 2 * N_ * F_];
        float wgt = rk[k];
        #pragma unroll
        for (int h = 0; h < H_; ++h) {
            acc[0][h] = fmaf(x0, wgt, acc[0][h]);
            acc[1][h] = fmaf(x1, wgt, acc[1][h]);
            acc[2][h] = fmaf(x2, wgt, acc[2][h]);
            wgt *= rk[k];
        }
    }

    // ---- publish raw boundary row (t = 3w+2), then blend in registers ----
    #pragma unroll
    for (int h = 0; h < H_; ++h) bnd[wave][h][lane] = acc[2][h];
    __syncthreads();

    #pragma unroll
    for (int h = 0; h < H_; ++h) {
        acc[2][h] = fmaf(0.8f, acc[2][h], 0.2f * acc[1][h]);
        acc[1][h] = fmaf(0.8f, acc[1][h], 0.2f * acc[0][h]);
    }
    if (wave > 0) {
        #pragma unroll
        for (int h = 0; h < H_; ++h)
            acc[0][h] = fmaf(0.8f, acc[0][h], 0.2f * bnd[wave - 1][h][lane]);
    }

    // ---- write A (hi/lo bf16 split) to LDS ----
    #pragma unroll
    for (int i = 0; i < 3; ++i)
        #pragma unroll
        for (int h = 0; h < H_; ++h) {
            int m = (t0 + i) * H_ + h;
            float v  = acc[i][h];
            short hi = f2bf(v);
            sm.ab.Ahi[m * AST + lane] = hi;
            sm.ab.Alo[m * AST + lane] = f2bf(v - bf2f(hi));
        }
    __syncthreads();

    // ---- Phase 2: MFMA GEMM; wave owns output cols [16w, 16w+16) ----
    const int colw = (wave << 4) + (lane & 15);
    const int kg   = lane >> 4;
    short8 bh[2], bl[2];
    #pragma unroll
    for (int kb = 0; kb < 2; ++kb) {
        const float* wp = W + colw * F_ + kb * 32 + kg * 8;
        #pragma unroll
        for (int j = 0; j < 8; ++j) {
            float wv = wp[j];
            short hi = f2bf(wv);
            bh[kb][j] = hi;
            bl[kb][j] = f2bf(wv - bf2f(hi));
        }
    }
    const float bs = bias[colw];

    f32x4 creg[6];
    #pragma unroll
    for (int mt = 0; mt < 6; ++mt) {
        const short* ap = &sm.ab.Ahi[(mt * 16 + (lane & 15)) * AST + kg * 8];
        const short* lp = &sm.ab.Alo[(mt * 16 + (lane & 15)) * AST + kg * 8];
        short8 a0 = *(const short8*)ap;
        short8 a1 = *(const short8*)(ap + 32);
        short8 l0 = *(const short8*)lp;
        short8 l1 = *(const short8*)(lp + 32);

        f32x4 c = {0.f, 0.f, 0.f, 0.f};
        c = __builtin_amdgcn_mfma_f32_16x16x32_bf16(a0, bl[0], c, 0, 0, 0);
        c = __builtin_amdgcn_mfma_f32_16x16x32_bf16(a1, bl[1], c, 0, 0, 0);
        c = __builtin_amdgcn_mfma_f32_16x16x32_bf16(l0, bh[0], c, 0, 0, 0);
        c = __builtin_amdgcn_mfma_f32_16x16x32_bf16(l1, bh[1], c, 0, 0, 0);
        c = __builtin_amdgcn_mfma_f32_16x16x32_bf16(a0, bh[0], c, 0, 0, 0);
        c = __builtin_amdgcn_mfma_f32_16x16x32_bf16(a1, bh[1], c, 0, 0, 0);
        creg[mt] = c;
    }

    // ---- stage C (bias+ReLU applied) into LDS, aliased over the A-tile ----
    __syncthreads();   // all MFMA reads of Ahi/Alo done before overwrite
    #pragma unroll
    for (int mt = 0; mt < 6; ++mt) {
        int m0 = mt * 16 + (lane >> 4) * 4;
        #pragma unroll
        for (int r = 0; r < 4; ++r)
            sm.Cst[(m0 + r) * CST + colw] = fmaxf(creg[mt][r] + bs, 0.f);
    }
    __syncthreads();

    // ---- cooperative, fully-coalesced float4 epilogue (1 KB per wave-store) ----
    const size_t ob = ((size_t)b * T_) * (size_t)(N_ * H_ * F_) + (size_t)n * (H_ * F_);
    #pragma unroll
    for (int it = 0; it < 6; ++it) {
        int j  = it * 256 + tid;      // float4 index, 0..1535
        int m  = j >> 4;              // row 0..95  (m = t*8 + h)
        int f4 = j & 15;
        int t  = m >> 3, h = m & 7;
        float4 v = *(const float4*)&sm.Cst[m * CST + f4 * 4];
        *(float4*)&out[ob + (size_t)t * (N_ * H_ * F_) + h * F_ + f4 * 4] = v;
    }
}

extern "C" void kernel_launch(void* const* d_in, const int* in_sizes, int n_in,
                              void* d_out, int out_size, void* d_ws, size_t ws_size,
                              hipStream_t stream) {
    const float* x    = (const float*)d_in[0];
    const float* dist = (const float*)d_in[1];
    const float* W    = (const float*)d_in[2];
    const float* bias = (const float*)d_in[3];
    const int*   idx  = (const int*)d_in[4];
    float* out = (float*)d_out;

    hipLaunchKernelGGL(gconv_mfma, dim3(B_ * N_), dim3(256), 0, stream,
                       x, dist, W, bias, idx, out);
}